// Round 1
// baseline (224.287 us; speedup 1.0000x reference)
//
#include <hip/hip_runtime.h>
#include <hip/hip_bf16.h>

// Problem constants
#define M_DIM   16384     // BATCH
#define K_DIM   512       // N_FEATURES
#define NNODES  4095
#define NPERM   4096      // permuted bottom-subtree columns (128 subtrees x 32)
#define NTOP    128       // top nodes 0..126 + 1 pad
#define NWROWS  (NPERM + NTOP)

// gemm_fold geometry (R13): BM=256, BN=128, BK=64, 8 waves, 3-ring LDS,
// counted-vmcnt phased schedule (T3+T4) + setprio (T5).
#define NBOT_BLOCKS (64 * 32)       // 64 m-tiles (256 rows) x 32 bottom n-tiles
#define NTOT_BLOCKS (NBOT_BLOCKS + 64)
#define RING    49152               // bytes per K-tile buffer: A 32K + B 16K
#define SLF_OFF (3 * RING)          // 147456; slf lives outside the ring
#define SMEM_BYTES (SLF_OFF + 512)
#define PT_STRIDE 135               // halves; odd stride breaks pow2 bank aliasing

typedef __bf16   bf16x8 __attribute__((ext_vector_type(8)));
typedef float    floatx4 __attribute__((ext_vector_type(4)));

// 4-inst sigmoid (rel err ~1e-7; absmax 3.9e-3 vs 1.06e-2 threshold)
__device__ __forceinline__ float sigmoidf_(float z) {
    return __builtin_amdgcn_rcpf(1.f + __expf(-z));
}

__device__ __forceinline__ void gld_lds16(const void* g, void* l) {
    __builtin_amdgcn_global_load_lds(
        (const __attribute__((address_space(1))) void*)g,
        (__attribute__((address_space(3))) void*)l, 16, 0, 0);
}

// ---------------- fused conversion: X->bf16, W->permuted bf16 ----------------
__global__ __launch_bounds__(256) void cvt_all(const float* __restrict__ X,
                                               const float* __restrict__ W,
                                               const float* __restrict__ bias,
                                               const float* __restrict__ scale,
                                               __hip_bfloat16* __restrict__ Xb,
                                               __hip_bfloat16* __restrict__ Wb,
                                               float* __restrict__ bp,
                                               float* __restrict__ sp) {
    const int bid = blockIdx.x;
    if (bid < 4096) {
        const int idx = (bid * 256 + threadIdx.x) * 8;
        float4 f0 = *reinterpret_cast<const float4*>(X + idx);
        float4 f1 = *reinterpret_cast<const float4*>(X + idx + 4);
        __hip_bfloat16 h[8];
        h[0] = __float2bfloat16(f0.x); h[1] = __float2bfloat16(f0.y);
        h[2] = __float2bfloat16(f0.z); h[3] = __float2bfloat16(f0.w);
        h[4] = __float2bfloat16(f1.x); h[5] = __float2bfloat16(f1.y);
        h[6] = __float2bfloat16(f1.z); h[7] = __float2bfloat16(f1.w);
        *reinterpret_cast<int4*>(Xb + idx) = *reinterpret_cast<int4*>(h);
        return;
    }
    const int idx = ((bid - 4096) * 256 + threadIdx.x) * 8;
    const int r = idx >> 9;
    const int k = idx & 511;
    // rows 0..4095: subtree t=r>>5, slot o=r&31:
    //   o<16: d11 q=o; <24: d10; <28: d9; <30: d8; 30: d7 root; 31: pad
    //   node = 2^d-1 + (t << (d-7)) + q.   rows 4096..4223: top node c (c<127)
    int node;
    if (r < NPERM) {
        const int t = r >> 5, o = r & 31;
        int d, q;
        if (o < 16)       { d = 11; q = o; }
        else if (o < 24)  { d = 10; q = o - 16; }
        else if (o < 28)  { d = 9;  q = o - 24; }
        else if (o < 30)  { d = 8;  q = o - 28; }
        else if (o == 30) { d = 7;  q = 0; }
        else              { d = -1; q = 0; }
        node = (d < 0) ? -1 : ((1 << d) - 1 + (t << (d - 7)) + q);
    } else {
        const int c = r - NPERM;
        node = (c < 127) ? c : -1;
    }
    __hip_bfloat16 h[8];
    if (node >= 0) {
        const float* src = W + (size_t)node * 512 + k;
        float4 f0 = *reinterpret_cast<const float4*>(src);
        float4 f1 = *reinterpret_cast<const float4*>(src + 4);
        h[0] = __float2bfloat16(f0.x); h[1] = __float2bfloat16(f0.y);
        h[2] = __float2bfloat16(f0.z); h[3] = __float2bfloat16(f0.w);
        h[4] = __float2bfloat16(f1.x); h[5] = __float2bfloat16(f1.y);
        h[6] = __float2bfloat16(f1.z); h[7] = __float2bfloat16(f1.w);
    } else {
        #pragma unroll
        for (int i = 0; i < 8; ++i) h[i] = __float2bfloat16(0.f);
    }
    *reinterpret_cast<int4*>(Wb + idx) = *reinterpret_cast<int4*>(h);
    if (k == 0) {
        bp[r] = (node >= 0) ? bias[node]  : 0.f;
        sp[r] = (node >= 0) ? scale[node] : 1.f;
    }
}

// ---------------- GEMM + sigmoid + bottom-5-level fold ----------------
// R13 structure: BM=256 x BN=128 x BK=64, 512 threads (8 waves, wave grid
// 4M x 2N, each wave 64x64 = acc[4][4]).  3-deep K-tile ring in LDS:
//   compute tile t from ring[t%3], stage tile t+2 into ring[(t+2)%3]
// -> staging never touches a buffer being read; retirement is tile-granular.
// Per K-tile: 2 phases {8 ds_read_b128 || 3 global_load_lds || raw s_barrier
// || setprio(1) 16xMFMA setprio(0)}.  Tile boundary: s_waitcnt vmcnt(6)
// (tile t+2's 6 loads stay IN FLIGHT across the barrier; T4) - drain-0 only
// at the t==6 boundary (pipeline tail).  Raw s_barrier (not __syncthreads)
// so the compiler cannot re-insert vmcnt(0) drains; all correctness fences
// are asm with "memory" clobber.  t-loop kept ROLLED (session R6: unroll
// races).  XOR swizzle: store-side pre-swizzled global src (swzb), read-side
// cb^xr -- unchanged from R5 (2-way conflicts = free).
__global__ __launch_bounds__(512, 1) void gemm_fold(
    const __hip_bfloat16* __restrict__ A,   // [16384][512]
    const __hip_bfloat16* __restrict__ B,   // [4224][512] permuted
    const float* __restrict__ bp,           // [4224]
    const float* __restrict__ sp,           // [4224]
    const float* __restrict__ leaves,       // [4096]
    float* __restrict__ partial,            // [16384][128]
    _Float16* __restrict__ ptop)            // [16384][128]
{
    __shared__ char smem[SMEM_BYTES] __attribute__((aligned(16)));
    _Float16* pt  = (_Float16*)smem;                 // epilogue overlay
    float*    slf = (float*)(smem + SLF_OFF);        // 128 floats, outside ring

    const int tid  = threadIdx.x;
    const int lane = tid & 63;
    const int wv   = tid >> 6;                       // 0..7
    const int bid  = blockIdx.x;
    int tile_m, tile_n;
    if (bid < NBOT_BLOCKS) { tile_m = bid >> 5; tile_n = bid & 31; }
    else                   { tile_m = bid - NBOT_BLOCKS; tile_n = 32; }
    const int m0 = tile_m * 256;
    const int n0 = tile_n * 128;

    const int wm = (wv >> 1) * 64;                   // 0,64,128,192
    const int wn = (wv & 1) * 64;                    // 0,64
    const int lrow = lane >> 3;                      // row within 8-row group
    const int swzb = ((lane & 7) ^ lrow) * 16;       // pre-swizzled k-block
    const int quad = lane >> 4;
    const int l15  = lane & 15;
    const int xr   = l15 & 7;                        // fragment-read XOR key

    // staging: per-thread global pointers (+128 B per K-tile) + LDS bases.
    // A: 4 loads/thread (256 rows), B: 2 loads/thread (128 rows).
    const char* gAp[4];
    const char* gBp[2];
    char* sA[4];
    char* sB[2];
    #pragma unroll
    for (int i = 0; i < 4; ++i) {
        const int rbase = i * 64 + wv * 8;           // wave-uniform, mult of 8
        gAp[i] = (const char*)(A + (size_t)(m0 + rbase + lrow) * K_DIM) + swzb;
        sA[i]  = smem + rbase * 128;
    }
    #pragma unroll
    for (int j = 0; j < 2; ++j) {
        const int rbase = j * 64 + wv * 8;
        gBp[j] = (const char*)(B + (size_t)(n0 + rbase + lrow) * K_DIM) + swzb;
        sB[j]  = smem + 32768 + rbase * 128;
    }

    floatx4 acc[4][4];
    #pragma unroll
    for (int i = 0; i < 4; ++i)
        #pragma unroll
        for (int j = 0; j < 4; ++j)
            acc[i][j] = (floatx4){0.f, 0.f, 0.f, 0.f};

    // prologue: tile0 -> ring0, tile1 -> ring1 (12 loads/thread in flight)
    #pragma unroll
    for (int i = 0; i < 4; ++i) { gld_lds16(gAp[i], sA[i]); gAp[i] += 128; }
    #pragma unroll
    for (int j = 0; j < 2; ++j) { gld_lds16(gBp[j], sB[j]); gBp[j] += 128; }
    #pragma unroll
    for (int i = 0; i < 4; ++i) { gld_lds16(gAp[i], sA[i] + RING); gAp[i] += 128; }
    #pragma unroll
    for (int j = 0; j < 2; ++j) { gld_lds16(gBp[j], sB[j] + RING); gBp[j] += 128; }
    asm volatile("s_waitcnt vmcnt(6)" ::: "memory");   // tile0 landed, tile1 in flight
    __builtin_amdgcn_s_barrier();

    int cur = 0;
    int stg = 2 * RING;
    #pragma unroll 1
    for (int t = 0; t < 8; ++t) {
        const __hip_bfloat16* cA = (const __hip_bfloat16*)(smem + cur);
        const __hip_bfloat16* cB = (const __hip_bfloat16*)(smem + cur + 32768);

        // ---- phase 0: kk = 0..31 ----
        {
            const int cb = quad ^ xr;
            bf16x8 af[4], bfr[4];
            #pragma unroll
            for (int i = 0; i < 4; ++i)
                af[i] = *reinterpret_cast<const bf16x8*>(
                    &cA[(wm + i * 16 + l15) * 64 + cb * 8]);
            #pragma unroll
            for (int j = 0; j < 4; ++j)
                bfr[j] = *reinterpret_cast<const bf16x8*>(
                    &cB[(wn + j * 16 + l15) * 64 + cb * 8]);
            if (t < 6) {
                gld_lds16(gAp[0], sA[0] + stg);
                gld_lds16(gAp[1], sA[1] + stg);
                gld_lds16(gBp[0], sB[0] + stg);
            }
            __builtin_amdgcn_s_barrier();
            __builtin_amdgcn_s_setprio(1);
            #pragma unroll
            for (int i = 0; i < 4; ++i)
                #pragma unroll
                for (int j = 0; j < 4; ++j)
                    acc[i][j] = __builtin_amdgcn_mfma_f32_16x16x32_bf16(
                        af[i], bfr[j], acc[i][j], 0, 0, 0);
            __builtin_amdgcn_s_setprio(0);
            __builtin_amdgcn_s_barrier();
        }

        // ---- phase 1: kk = 32..63 ----
        {
            const int cb = (4 + quad) ^ xr;
            bf16x8 af[4], bfr[4];
            #pragma unroll
            for (int i = 0; i < 4; ++i)
                af[i] = *reinterpret_cast<const bf16x8*>(
                    &cA[(wm + i * 16 + l15) * 64 + cb * 8]);
            #pragma unroll
            for (int j = 0; j < 4; ++j)
                bfr[j] = *reinterpret_cast<const bf16x8*>(
                    &cB[(wn + j * 16 + l15) * 64 + cb * 8]);
            if (t < 6) {
                gld_lds16(gAp[2], sA[2] + stg);
                gld_lds16(gAp[3], sA[3] + stg);
                gld_lds16(gBp[1], sB[1] + stg);
                #pragma unroll
                for (int i = 0; i < 4; ++i) gAp[i] += 128;
                gBp[0] += 128; gBp[1] += 128;
            }
            __builtin_amdgcn_s_barrier();
            __builtin_amdgcn_s_setprio(1);
            #pragma unroll
            for (int i = 0; i < 4; ++i)
                #pragma unroll
                for (int j = 0; j < 4; ++j)
                    acc[i][j] = __builtin_amdgcn_mfma_f32_16x16x32_bf16(
                        af[i], bfr[j], acc[i][j], 0, 0, 0);
            __builtin_amdgcn_s_setprio(0);
            // tile boundary: publish tile t+1 (staged during t-1).  In flight:
            // tile t+2's 6 loads (issued this iter) -> vmcnt(6).  At t==6
            // nothing was issued this iter, so drain to 0 for tile 7 (tail).
            if (t < 6) {
                asm volatile("s_waitcnt vmcnt(6)" ::: "memory");
            } else if (t == 6) {
                asm volatile("s_waitcnt vmcnt(0)" ::: "memory");
            }
            __builtin_amdgcn_s_barrier();
        }

        cur = (cur == 2 * RING) ? 0 : cur + RING;
        stg = (stg == 2 * RING) ? 0 : stg + RING;
    }
    __syncthreads();         // full fence: all compute done before pt overlay

    float bn[4], sn[4];
    #pragma unroll
    for (int j = 0; j < 4; ++j) {
        const int n = n0 + wn + j * 16 + l15;
        bn[j] = bp[n];
        sn[j] = sp[n];
    }

    if (tile_n == 32) {
        // top-node tile: p straight to global
        #pragma unroll
        for (int i = 0; i < 4; ++i) {
            #pragma unroll
            for (int r = 0; r < 4; ++r) {
                const int m = m0 + wm + i * 16 + quad * 4 + r;
                #pragma unroll
                for (int j = 0; j < 4; ++j) {
                    const int col = wn + j * 16 + l15;
                    ptop[(size_t)m * 128 + col] =
                        (_Float16)sigmoidf_((acc[i][j][r] + bn[j]) * sn[j]);
                }
            }
        }
        return;
    }

    if (tid < 128) slf[tid] = sigmoidf_(leaves[n0 + tid]);

    // p -> LDS (fp16), then per-subtree fold of the bottom 5 levels
    #pragma unroll
    for (int i = 0; i < 4; ++i) {
        #pragma unroll
        for (int r = 0; r < 4; ++r) {
            const int row = wm + i * 16 + quad * 4 + r;
            #pragma unroll
            for (int j = 0; j < 4; ++j) {
                const int col = wn + j * 16 + l15;
                pt[row * PT_STRIDE + col] =
                    (_Float16)sigmoidf_((acc[i][j][r] + bn[j]) * sn[j]);
            }
        }
    }
    __syncthreads();

    #pragma unroll
    for (int z = 0; z < 2; ++z) {
        const int task = tid + z * 512;      // 1024 = 256 rows x 4 subtrees
        const int row  = task >> 2;
        const int st   = task & 3;
        const _Float16* pp = pt + row * PT_STRIDE + st * 32;
        const float*    sl = slf + st * 32;
        float v[16];
        #pragma unroll
        for (int q = 0; q < 16; ++q) {
            const float p = (float)pp[q];
            v[q] = p * sl[2 * q] + (1.f - p) * sl[2 * q + 1];
        }
        #pragma unroll
        for (int q = 0; q < 8; ++q) {
            const float p = (float)pp[16 + q];
            v[q] = p * v[2 * q] + (1.f - p) * v[2 * q + 1];
        }
        #pragma unroll
        for (int q = 0; q < 4; ++q) {
            const float p = (float)pp[24 + q];
            v[q] = p * v[2 * q] + (1.f - p) * v[2 * q + 1];
        }
        #pragma unroll
        for (int q = 0; q < 2; ++q) {
            const float p = (float)pp[28 + q];
            v[q] = p * v[2 * q] + (1.f - p) * v[2 * q + 1];
        }
        const float p7 = (float)pp[30];
        partial[(size_t)(m0 + row) * 128 + tile_n * 4 + st] =
            p7 * v[0] + (1.f - p7) * v[1];
    }
}

// ---------------- final top-7-level fold ----------------
__global__ __launch_bounds__(256) void final_fold(
    const float* __restrict__ partial,       // [16384][128]
    const _Float16* __restrict__ ptop,       // [16384][128], node c at col c
    float* __restrict__ out)                 // [16384]
{
    __shared__ float    pL[64 * 129];        // odd dword stride
    __shared__ _Float16 pq[64 * 134];

    const int tid = threadIdx.x;
    const int m0  = blockIdx.x * 64;

    #pragma unroll
    for (int it = 0; it < 32; ++it) {
        const int idx = tid + it * 256;      // 8192 = 64*128
        const int row = idx >> 7;
        const int c   = idx & 127;
        pL[row * 129 + c] = partial[(size_t)(m0 + row) * 128 + c];
        pq[row * 134 + c] = ptop[(size_t)(m0 + row) * 128 + c];
    }
    __syncthreads();

    if (tid < 64) {
        float* v = pL + tid * 129;
        const _Float16* pr = pq + tid * 134;
        #pragma unroll
        for (int d = 6; d >= 1; --d) {
            const int base = (1 << d) - 1;
            const int cnt  = 1 << d;
            for (int q = 0; q < cnt; ++q) {
                const float p = (float)pr[base + q];
                v[q] = p * v[2 * q] + (1.f - p) * v[2 * q + 1];
            }
        }
        const float p0 = (float)pr[0];
        out[m0 + tid] = p0 * v[0] + (1.f - p0) * v[1];
    }
}

// ---------------- fp32 fallback (only if workspace too small) ----------------
__global__ __launch_bounds__(256) void tnn_fallback(
    const float* __restrict__ X, const float* __restrict__ W,
    const float* __restrict__ bias, const float* __restrict__ scale,
    const float* __restrict__ leaves, float* __restrict__ out)
{
    __shared__ float xr[512];
    __shared__ float sl[4096];
    __shared__ float pp[4096];
    __shared__ float v0[2048];
    __shared__ float v1[1024];
    const int tid  = threadIdx.x;
    const int lane = tid & 63;
    const int wv   = tid >> 6;
    const int b    = blockIdx.x;
    for (int i = tid; i < 512;  i += 256) xr[i] = X[(size_t)b * 512 + i];
    for (int i = tid; i < 4096; i += 256) sl[i] = sigmoidf_(leaves[i]);
    __syncthreads();
    for (int n = wv; n < NNODES; n += 4) {
        float sum = 0.f;
        const float* wr = W + (size_t)n * 512;
        for (int k = lane; k < 512; k += 64) sum += xr[k] * wr[k];
        #pragma unroll
        for (int off = 32; off; off >>= 1) sum += __shfl_xor(sum, off);
        if (lane == 0) pp[n] = sigmoidf_((sum + bias[n]) * scale[n]);
    }
    __syncthreads();
    for (int j = tid; j < 2048; j += 256) {
        const float p = pp[2047 + j];
        v0[j] = p * sl[2 * j] + (1.f - p) * sl[2 * j + 1];
    }
    __syncthreads();
    float* src = v0;
    float* dst = v1;
    for (int d = 10; d >= 0; --d) {
        const int width = 1 << d;
        const int start = width - 1;
        for (int j = tid; j < width; j += 256) {
            const float p = pp[start + j];
            dst[j] = p * src[2 * j] + (1.f - p) * src[2 * j + 1];
        }
        __syncthreads();
        float* t = src; src = dst; dst = t;
    }
    if (tid == 0) out[b] = src[0];
}

extern "C" void kernel_launch(void* const* d_in, const int* in_sizes, int n_in,
                              void* d_out, int out_size, void* d_ws, size_t ws_size,
                              hipStream_t stream) {
    const float* X      = (const float*)d_in[0];
    const float* W      = (const float*)d_in[1];
    const float* bias   = (const float*)d_in[2];
    const float* scale  = (const float*)d_in[3];
    const float* leaves = (const float*)d_in[4];
    float* out = (float*)d_out;

    const size_t offX  = 0;
    const size_t offW  = (size_t)M_DIM * K_DIM * 2;                 // 16 MB
    const size_t offB  = offW + (size_t)NWROWS * K_DIM * 2;         // +4.125 MB
    const size_t offS  = offB + (size_t)NWROWS * 4;
    const size_t offP  = offS + (size_t)NWROWS * 4;
    const size_t offT  = offP + (size_t)M_DIM * 128 * 4;            // +8 MB
    const size_t need  = offT + (size_t)M_DIM * 128 * 2;            // +4 MB

    if (ws_size >= need) {
        __hip_bfloat16* Xb = (__hip_bfloat16*)((char*)d_ws + offX);
        __hip_bfloat16* Wb = (__hip_bfloat16*)((char*)d_ws + offW);
        float* bp = (float*)((char*)d_ws + offB);
        float* sp = (float*)((char*)d_ws + offS);
        float* partial = (float*)((char*)d_ws + offP);
        _Float16* ptop = (_Float16*)((char*)d_ws + offT);
        cvt_all<<<4096 + 1056, 256, 0, stream>>>(X, W, bias, scale, Xb, Wb, bp, sp);
        gemm_fold<<<NTOT_BLOCKS, 512, 0, stream>>>(
            Xb, Wb, bp, sp, leaves, partial, ptop);
        final_fold<<<M_DIM / 64, 256, 0, stream>>>(partial, ptop, out);
    } else {
        tnn_fallback<<<M_DIM, 256, 0, stream>>>(X, W, bias, scale, leaves, out);
    }
}

// Round 2
// 195.048 us; speedup vs baseline: 1.1499x; 1.1499x over previous
//
#include <hip/hip_runtime.h>
#include <hip/hip_bf16.h>

// Problem constants
#define M_DIM   16384     // BATCH
#define K_DIM   512       // N_FEATURES
#define NNODES  4095
#define NPERM   4096      // permuted bottom-subtree columns (128 subtrees x 32)
#define NTOP    128       // top nodes 0..126 + 1 pad
#define NWROWS  (NPERM + NTOP)

// gemm_fold geometry (R14): block 256x128, 4 waves (2M x 2N), wave tile
// 128x64, BK=32, double-buffered, 2 blocks/CU.  LDS-BW-bound analysis:
// FLOP/LDS-byte = Wm*Wn/(Wm+Wn): 64x64 -> 32, 128x64 -> 42.7 (1.34x).
#define NBOT_BLOCKS (64 * 32)       // 64 m-tiles (256 rows) x 32 bottom n-tiles
#define NTOT_BLOCKS (NBOT_BLOCKS + 64)
#define BUFB    24576               // bytes per (A+B) buffer: A 16K + B 8K
#define PT_STRIDE 135               // halves; odd stride breaks pow2 bank aliasing
#define SLF_OFF (256 * PT_STRIDE * 2)   // 69120; after pt overlay
#define SMEM_BYTES (SLF_OFF + 512)      // 69632 -> 2 blocks/CU (139264 <= 160K)

typedef __bf16   bf16x8 __attribute__((ext_vector_type(8)));
typedef float    floatx4 __attribute__((ext_vector_type(4)));

// 4-inst sigmoid (rel err ~1e-7; absmax 3.9e-3 vs 1.06e-2 threshold)
__device__ __forceinline__ float sigmoidf_(float z) {
    return __builtin_amdgcn_rcpf(1.f + __expf(-z));
}

__device__ __forceinline__ void gld_lds16(const void* g, void* l) {
    __builtin_amdgcn_global_load_lds(
        (const __attribute__((address_space(1))) void*)g,
        (__attribute__((address_space(3))) void*)l, 16, 0, 0);
}

// ---------------- fused conversion: X->bf16, W->permuted bf16 ----------------
__global__ __launch_bounds__(256) void cvt_all(const float* __restrict__ X,
                                               const float* __restrict__ W,
                                               const float* __restrict__ bias,
                                               const float* __restrict__ scale,
                                               __hip_bfloat16* __restrict__ Xb,
                                               __hip_bfloat16* __restrict__ Wb,
                                               float* __restrict__ bp,
                                               float* __restrict__ sp) {
    const int bid = blockIdx.x;
    if (bid < 4096) {
        const int idx = (bid * 256 + threadIdx.x) * 8;
        float4 f0 = *reinterpret_cast<const float4*>(X + idx);
        float4 f1 = *reinterpret_cast<const float4*>(X + idx + 4);
        __hip_bfloat16 h[8];
        h[0] = __float2bfloat16(f0.x); h[1] = __float2bfloat16(f0.y);
        h[2] = __float2bfloat16(f0.z); h[3] = __float2bfloat16(f0.w);
        h[4] = __float2bfloat16(f1.x); h[5] = __float2bfloat16(f1.y);
        h[6] = __float2bfloat16(f1.z); h[7] = __float2bfloat16(f1.w);
        *reinterpret_cast<int4*>(Xb + idx) = *reinterpret_cast<int4*>(h);
        return;
    }
    const int idx = ((bid - 4096) * 256 + threadIdx.x) * 8;
    const int r = idx >> 9;
    const int k = idx & 511;
    // rows 0..4095: subtree t=r>>5, slot o=r&31:
    //   o<16: d11 q=o; <24: d10; <28: d9; <30: d8; 30: d7 root; 31: pad
    //   node = 2^d-1 + (t << (d-7)) + q.   rows 4096..4223: top node c (c<127)
    int node;
    if (r < NPERM) {
        const int t = r >> 5, o = r & 31;
        int d, q;
        if (o < 16)       { d = 11; q = o; }
        else if (o < 24)  { d = 10; q = o - 16; }
        else if (o < 28)  { d = 9;  q = o - 24; }
        else if (o < 30)  { d = 8;  q = o - 28; }
        else if (o == 30) { d = 7;  q = 0; }
        else              { d = -1; q = 0; }
        node = (d < 0) ? -1 : ((1 << d) - 1 + (t << (d - 7)) + q);
    } else {
        const int c = r - NPERM;
        node = (c < 127) ? c : -1;
    }
    __hip_bfloat16 h[8];
    if (node >= 0) {
        const float* src = W + (size_t)node * 512 + k;
        float4 f0 = *reinterpret_cast<const float4*>(src);
        float4 f1 = *reinterpret_cast<const float4*>(src + 4);
        h[0] = __float2bfloat16(f0.x); h[1] = __float2bfloat16(f0.y);
        h[2] = __float2bfloat16(f0.z); h[3] = __float2bfloat16(f0.w);
        h[4] = __float2bfloat16(f1.x); h[5] = __float2bfloat16(f1.y);
        h[6] = __float2bfloat16(f1.z); h[7] = __float2bfloat16(f1.w);
    } else {
        #pragma unroll
        for (int i = 0; i < 8; ++i) h[i] = __float2bfloat16(0.f);
    }
    *reinterpret_cast<int4*>(Wb + idx) = *reinterpret_cast<int4*>(h);
    if (k == 0) {
        bp[r] = (node >= 0) ? bias[node]  : 0.f;
        sp[r] = (node >= 0) ? scale[node] : 1.f;
    }
}

// ---------------- GEMM + sigmoid + bottom-5-level fold ----------------
// R14: proven R8/R12 loop skeleton (one __syncthreads per K-step, stage-then-
// compute dbuf, ROLLED loop) with 128x64 wave tiles to cut LDS bytes/FLOP.
// BK=32 bank hazard (row stride 64 B aliases every 2 rows) fixed by a 2-bit
// XOR swizzle: k-block stored at blk^(row&3) via PRE-SWIZZLED GLOBAL SRC
// (gld_lds dest must stay linear, m104), read back with cb = quad^(l15&3).
// Bank audit: 8 lanes per 4-bank group, uniform -> 8-cycle minimum per
// ds_read_b128, strictly conflict-free.
// R13 lesson: phase barriers around MFMA serialize ds_read vs MFMA and
// 1 block/CU kills inter-block overlap -> MfmaUtil 21.5%.  Reverted.
__global__ __launch_bounds__(256, 2) void gemm_fold(
    const __hip_bfloat16* __restrict__ A,   // [16384][512]
    const __hip_bfloat16* __restrict__ B,   // [4224][512] permuted
    const float* __restrict__ bp,           // [4224]
    const float* __restrict__ sp,           // [4224]
    const float* __restrict__ leaves,       // [4096]
    float* __restrict__ partial,            // [16384][128]
    _Float16* __restrict__ ptop)            // [16384][128]
{
    __shared__ char smem[SMEM_BYTES] __attribute__((aligned(16)));
    _Float16* pt  = (_Float16*)smem;                 // epilogue overlay
    float*    slf = (float*)(smem + SLF_OFF);        // 128 floats, beyond bufs

    const int tid  = threadIdx.x;
    const int lane = tid & 63;
    const int wv   = tid >> 6;                       // 0..3
    const int bid  = blockIdx.x;
    int tile_m, tile_n;
    if (bid < NBOT_BLOCKS) { tile_m = bid >> 5; tile_n = bid & 31; }
    else                   { tile_m = bid - NBOT_BLOCKS; tile_n = 32; }
    const int m0 = tile_m * 256;
    const int n0 = tile_n * 128;

    // slf lives beyond the GEMM buffers (offset 69120 > 49152): safe early.
    if (tile_n < 32 && tid < 128) slf[tid] = sigmoidf_(leaves[n0 + tid]);

    const int wvm = wv >> 1;                         // 0..1  (128-row half)
    const int wvn = wv & 1;                          // 0..1  (64-col half)
    const int quad = lane >> 4;
    const int l15  = lane & 15;
    const int cbS  = (quad ^ (l15 & 3)) * 8;         // swizzled k-block (elems)

    // staging: LDS dest linear (wave-uniform base + lane*16); global src
    // pre-swizzled.  Per call: 1 wave covers 16 rows x 4 k-blocks = 1024 B.
    const int srow = lane >> 2;                      // 0..15 row within call
    const int swz  = (((lane & 3) ^ (srow & 3)) * 16);
    const char* gAp[4];
    const char* gBp[2];
    char* sA[4];
    char* sB[2];
    #pragma unroll
    for (int c = 0; c < 4; ++c) {
        const int rbase = c * 64 + wv * 16;          // wave-uniform
        gAp[c] = (const char*)(A + (size_t)(m0 + rbase + srow) * K_DIM) + swz;
        sA[c]  = smem + rbase * 64;
    }
    #pragma unroll
    for (int c = 0; c < 2; ++c) {
        const int rbase = c * 64 + wv * 16;
        gBp[c] = (const char*)(B + (size_t)(n0 + rbase + srow) * K_DIM) + swz;
        sB[c]  = smem + 16384 + rbase * 64;
    }

    floatx4 acc[8][4];
    #pragma unroll
    for (int i = 0; i < 8; ++i)
        #pragma unroll
        for (int j = 0; j < 4; ++j)
            acc[i][j] = (floatx4){0.f, 0.f, 0.f, 0.f};

    // prologue: stage k0=0 into buf0
    #pragma unroll
    for (int c = 0; c < 4; ++c) { gld_lds16(gAp[c], sA[c]); gAp[c] += 64; }
    #pragma unroll
    for (int c = 0; c < 2; ++c) { gld_lds16(gBp[c], sB[c]); gBp[c] += 64; }

    #pragma unroll 1
    for (int k0 = 0; k0 < 16; ++k0) {
        __syncthreads();     // publishes buf(k0) (vmcnt0 drain) + role swap
        if (k0 < 15) {
            const int boff = ((k0 + 1) & 1) * BUFB;
            #pragma unroll
            for (int c = 0; c < 4; ++c) { gld_lds16(gAp[c], sA[c] + boff); gAp[c] += 64; }
            #pragma unroll
            for (int c = 0; c < 2; ++c) { gld_lds16(gBp[c], sB[c] + boff); gBp[c] += 64; }
        }
        const __hip_bfloat16* cA =
            (const __hip_bfloat16*)(smem + (k0 & 1) * BUFB);
        const __hip_bfloat16* cB = cA + 8192;        // B at +16384 bytes

        bf16x8 bfr[4];
        #pragma unroll
        for (int j = 0; j < 4; ++j)
            bfr[j] = *reinterpret_cast<const bf16x8*>(
                &cB[(wvn * 64 + j * 16 + l15) * 32 + cbS]);
        #pragma unroll
        for (int i = 0; i < 8; ++i) {
            const bf16x8 af = *reinterpret_cast<const bf16x8*>(
                &cA[(wvm * 128 + i * 16 + l15) * 32 + cbS]);
            #pragma unroll
            for (int j = 0; j < 4; ++j)
                acc[i][j] = __builtin_amdgcn_mfma_f32_16x16x32_bf16(
                    af, bfr[j], acc[i][j], 0, 0, 0);
        }
    }
    __syncthreads();         // all compute done before pt overlays buffers

    float bn[4], sn[4];
    #pragma unroll
    for (int j = 0; j < 4; ++j) {
        const int n = n0 + wvn * 64 + j * 16 + l15;
        bn[j] = bp[n];
        sn[j] = sp[n];
    }

    if (tile_n == 32) {
        // top-node tile: p straight to global
        #pragma unroll
        for (int i = 0; i < 8; ++i) {
            #pragma unroll
            for (int r = 0; r < 4; ++r) {
                const int m = m0 + wvm * 128 + i * 16 + quad * 4 + r;
                #pragma unroll
                for (int j = 0; j < 4; ++j) {
                    const int col = wvn * 64 + j * 16 + l15;
                    ptop[(size_t)m * 128 + col] =
                        (_Float16)sigmoidf_((acc[i][j][r] + bn[j]) * sn[j]);
                }
            }
        }
        return;
    }

    // p -> LDS (fp16), then per-subtree fold of the bottom 5 levels
    #pragma unroll
    for (int i = 0; i < 8; ++i) {
        #pragma unroll
        for (int r = 0; r < 4; ++r) {
            const int row = wvm * 128 + i * 16 + quad * 4 + r;
            #pragma unroll
            for (int j = 0; j < 4; ++j) {
                const int col = wvn * 64 + j * 16 + l15;
                pt[row * PT_STRIDE + col] =
                    (_Float16)sigmoidf_((acc[i][j][r] + bn[j]) * sn[j]);
            }
        }
    }
    __syncthreads();

    #pragma unroll
    for (int z = 0; z < 4; ++z) {
        const int task = tid + z * 256;      // 1024 = 256 rows x 4 subtrees
        const int row  = task >> 2;
        const int st   = task & 3;
        const _Float16* pp = pt + row * PT_STRIDE + st * 32;
        const float*    sl = slf + st * 32;
        float v[16];
        #pragma unroll
        for (int q = 0; q < 16; ++q) {
            const float p = (float)pp[q];
            v[q] = p * sl[2 * q] + (1.f - p) * sl[2 * q + 1];
        }
        #pragma unroll
        for (int q = 0; q < 8; ++q) {
            const float p = (float)pp[16 + q];
            v[q] = p * v[2 * q] + (1.f - p) * v[2 * q + 1];
        }
        #pragma unroll
        for (int q = 0; q < 4; ++q) {
            const float p = (float)pp[24 + q];
            v[q] = p * v[2 * q] + (1.f - p) * v[2 * q + 1];
        }
        #pragma unroll
        for (int q = 0; q < 2; ++q) {
            const float p = (float)pp[28 + q];
            v[q] = p * v[2 * q] + (1.f - p) * v[2 * q + 1];
        }
        const float p7 = (float)pp[30];
        partial[(size_t)(m0 + row) * 128 + tile_n * 4 + st] =
            p7 * v[0] + (1.f - p7) * v[1];
    }
}

// ---------------- final top-7-level fold ----------------
__global__ __launch_bounds__(256) void final_fold(
    const float* __restrict__ partial,       // [16384][128]
    const _Float16* __restrict__ ptop,       // [16384][128], node c at col c
    float* __restrict__ out)                 // [16384]
{
    __shared__ float    pL[64 * 129];        // odd dword stride
    __shared__ _Float16 pq[64 * 134];

    const int tid = threadIdx.x;
    const int m0  = blockIdx.x * 64;

    #pragma unroll
    for (int it = 0; it < 32; ++it) {
        const int idx = tid + it * 256;      // 8192 = 64*128
        const int row = idx >> 7;
        const int c   = idx & 127;
        pL[row * 129 + c] = partial[(size_t)(m0 + row) * 128 + c];
        pq[row * 134 + c] = ptop[(size_t)(m0 + row) * 128 + c];
    }
    __syncthreads();

    if (tid < 64) {
        float* v = pL + tid * 129;
        const _Float16* pr = pq + tid * 134;
        #pragma unroll
        for (int d = 6; d >= 1; --d) {
            const int base = (1 << d) - 1;
            const int cnt  = 1 << d;
            for (int q = 0; q < cnt; ++q) {
                const float p = (float)pr[base + q];
                v[q] = p * v[2 * q] + (1.f - p) * v[2 * q + 1];
            }
        }
        const float p0 = (float)pr[0];
        out[m0 + tid] = p0 * v[0] + (1.f - p0) * v[1];
    }
}

// ---------------- fp32 fallback (only if workspace too small) ----------------
__global__ __launch_bounds__(256) void tnn_fallback(
    const float* __restrict__ X, const float* __restrict__ W,
    const float* __restrict__ bias, const float* __restrict__ scale,
    const float* __restrict__ leaves, float* __restrict__ out)
{
    __shared__ float xr[512];
    __shared__ float sl[4096];
    __shared__ float pp[4096];
    __shared__ float v0[2048];
    __shared__ float v1[1024];
    const int tid  = threadIdx.x;
    const int lane = tid & 63;
    const int wv   = tid >> 6;
    const int b    = blockIdx.x;
    for (int i = tid; i < 512;  i += 256) xr[i] = X[(size_t)b * 512 + i];
    for (int i = tid; i < 4096; i += 256) sl[i] = sigmoidf_(leaves[i]);
    __syncthreads();
    for (int n = wv; n < NNODES; n += 4) {
        float sum = 0.f;
        const float* wr = W + (size_t)n * 512;
        for (int k = lane; k < 512; k += 64) sum += xr[k] * wr[k];
        #pragma unroll
        for (int off = 32; off; off >>= 1) sum += __shfl_xor(sum, off);
        if (lane == 0) pp[n] = sigmoidf_((sum + bias[n]) * scale[n]);
    }
    __syncthreads();
    for (int j = tid; j < 2048; j += 256) {
        const float p = pp[2047 + j];
        v0[j] = p * sl[2 * j] + (1.f - p) * sl[2 * j + 1];
    }
    __syncthreads();
    float* src = v0;
    float* dst = v1;
    for (int d = 10; d >= 0; --d) {
        const int width = 1 << d;
        const int start = width - 1;
        for (int j = tid; j < width; j += 256) {
            const float p = pp[start + j];
            dst[j] = p * src[2 * j] + (1.f - p) * src[2 * j + 1];
        }
        __syncthreads();
        float* t = src; src = dst; dst = t;
    }
    if (tid == 0) out[b] = src[0];
}

extern "C" void kernel_launch(void* const* d_in, const int* in_sizes, int n_in,
                              void* d_out, int out_size, void* d_ws, size_t ws_size,
                              hipStream_t stream) {
    const float* X      = (const float*)d_in[0];
    const float* W      = (const float*)d_in[1];
    const float* bias   = (const float*)d_in[2];
    const float* scale  = (const float*)d_in[3];
    const float* leaves = (const float*)d_in[4];
    float* out = (float*)d_out;

    const size_t offX  = 0;
    const size_t offW  = (size_t)M_DIM * K_DIM * 2;                 // 16 MB
    const size_t offB  = offW + (size_t)NWROWS * K_DIM * 2;         // +4.125 MB
    const size_t offS  = offB + (size_t)NWROWS * 4;
    const size_t offP  = offS + (size_t)NWROWS * 4;
    const size_t offT  = offP + (size_t)M_DIM * 128 * 4;            // +8 MB
    const size_t need  = offT + (size_t)M_DIM * 128 * 2;            // +4 MB

    if (ws_size >= need) {
        __hip_bfloat16* Xb = (__hip_bfloat16*)((char*)d_ws + offX);
        __hip_bfloat16* Wb = (__hip_bfloat16*)((char*)d_ws + offW);
        float* bp = (float*)((char*)d_ws + offB);
        float* sp = (float*)((char*)d_ws + offS);
        float* partial = (float*)((char*)d_ws + offP);
        _Float16* ptop = (_Float16*)((char*)d_ws + offT);
        cvt_all<<<4096 + 1056, 256, 0, stream>>>(X, W, bias, scale, Xb, Wb, bp, sp);
        gemm_fold<<<NTOT_BLOCKS, 256, 0, stream>>>(
            Xb, Wb, bp, sp, leaves, partial, ptop);
        final_fold<<<M_DIM / 64, 256, 0, stream>>>(partial, ptop, out);
    } else {
        tnn_fallback<<<M_DIM, 256, 0, stream>>>(X, W, bias, scale, leaves, out);
    }
}